// Round 6
// baseline (277.643 us; speedup 1.0000x reference)
//
#include <hip/hip_runtime.h>
#include <hip/hip_bf16.h>
#include <hip/hip_cooperative_groups.h>

namespace cg = cooperative_groups;

// Problem constants
constexpr int Dd = 1024;           // feature dim
constexpr int Tt = 2048;           // sequence length
constexpr int Bb = 4;              // batch
constexpr int Rr = Bb * Tt;        // GEMM rows = 8192
constexpr int NCH = 128;           // scan chunks per batch row
constexpr int CL  = 16;            // steps per chunk
constexpr int GRID = 512;          // = Bb*NCH scan blocks = 64x8 GEMM tiles
constexpr int CBL = 64;            // c-reduction blocks

typedef __attribute__((ext_vector_type(4))) float f32x4;
typedef __attribute__((ext_vector_type(8))) short bf16x8;

__device__ __forceinline__ float sigmoidf_(float v) {
    return 1.0f / (1.0f + expf(-v));
}

__device__ __forceinline__ short bf16bits(float f) {
    union { __hip_bfloat16 b; short s; } u;
    u.b = __float2bfloat16(f);
    return u.s;
}

__device__ __forceinline__ void async16(const void* g, void* l) {
    __builtin_amdgcn_global_load_lds(
        (const __attribute__((address_space(1))) unsigned int*)g,
        (__attribute__((address_space(3))) unsigned int*)l,
        16, 0, 0);
}

// ---------------------------------------------------------------------------
// Phase bodies (shared between mega-kernel and fallback kernels)

// P1a: chunk-local EMA end value (thread owns 4 consecutive d)
__device__ __forceinline__ void p1_scan_end(const float* __restrict__ x,
                                            float dd, int b, int ch, int tid,
                                            float* __restrict__ endv) {
    const size_t base = ((size_t)b * Tt + (size_t)ch * CL) * Dd + tid * 4;
    f32x4 e = (f32x4){0.f, 0.f, 0.f, 0.f};
    #pragma unroll
    for (int t = 0; t < CL; ++t) {
        f32x4 v = *(const f32x4*)&x[base + (size_t)t * Dd];
        e = dd * e + v;
    }
    *(f32x4*)&endv[((size_t)b * NCH + ch) * Dd + tid * 4] = e;
}

// P1b: circulant c[n] = sum_m unbind[m]*bind[(m+n)%D]; block does 16 n's.
__device__ __forceinline__ void p1_cblock(const float* __restrict__ bind,
                                          const float* __restrict__ unbind,
                                          int cb, int tid,
                                          float* sb, float* su, float* sp,
                                          float* __restrict__ c) {
    for (int j = tid; j < Dd; j += 256) { sb[j] = bind[j]; su[j] = unbind[j]; }
    __syncthreads();
    const int n_loc = tid >> 4;
    const int seg = tid & 15;
    const int n = cb * 16 + n_loc;
    float acc = 0.f;
    #pragma unroll 8
    for (int i = 0; i < 64; ++i) {
        const int m = i * 16 + seg;
        acc = fmaf(su[m], sb[(m + n) & (Dd - 1)], acc);
    }
    sp[tid] = acc;
    __syncthreads();
    if (tid < 16) {
        float s = 0.f;
        #pragma unroll
        for (int j = 0; j < 16; ++j) s += sp[tid * 16 + j];
        c[cb * 16 + tid] = s;
    }
}

// P2a: carry recombine + full scan, write bf16 xs once
__device__ __forceinline__ void p2_scan_write(const float* __restrict__ x,
                                              float dd, int b, int ch, int tid,
                                              const float* __restrict__ endv,
                                              __hip_bfloat16* __restrict__ xs) {
    const float dL = powf(dd, (float)CL);
    f32x4 h = (f32x4){0.f, 0.f, 0.f, 0.f};
    const float* ep = endv + ((size_t)b * NCH) * Dd + tid * 4;
    #pragma unroll 8
    for (int cc = 0; cc < ch; ++cc)
        h = dL * h + *(const f32x4*)&ep[(size_t)cc * Dd];
    const size_t base = ((size_t)b * Tt + (size_t)ch * CL) * Dd + tid * 4;
    #pragma unroll
    for (int t = 0; t < CL; ++t) {
        f32x4 v = *(const f32x4*)&x[base + (size_t)t * Dd];
        h = dd * h + v;
        short4 o;
        o.x = bf16bits(h[0]); o.y = bf16bits(h[1]);
        o.z = bf16bits(h[2]); o.w = bf16bits(h[3]);
        *(short4*)&xs[base + (size_t)t * Dd] = o;
    }
}

// P2b: Wt[n][k] = bf16(c[(n-k) mod D]); 8 outputs/thread, wb in [0,512)
__device__ __forceinline__ void p2_wbuild(const float* __restrict__ c,
                                          int wb, int tid,
                                          __hip_bfloat16* __restrict__ wt) {
    const int idx8 = wb * 256 + tid;
    const int n = idx8 >> 7;
    const int k0 = (idx8 & 127) * 8;
    bf16x8 v;
    #pragma unroll
    for (int j = 0; j < 8; ++j)
        v[j] = bf16bits(c[(n - (k0 + j)) & (Dd - 1)]);
    *(bf16x8*)&wt[(size_t)n * Dd + k0] = v;
}

// P3: one 128x128 output tile of out = x + g*(xs @ Wt^T)
__device__ __forceinline__ void p3_gemm_tile(const __hip_bfloat16* __restrict__ A,
                                             const __hip_bfloat16* __restrict__ Wt,
                                             const float* __restrict__ x,
                                             float g, int tile_m, int tile_n,
                                             int tid,
                                             __hip_bfloat16* sA, __hip_bfloat16* sB,
                                             float* __restrict__ out) {
    const int wave = tid >> 6;
    const int lane = tid & 63;
    const int wm = (wave & 1) * 64;
    const int wn = (wave >> 1) * 64;

    f32x4 acc[4][4];
    #pragma unroll
    for (int i = 0; i < 4; ++i)
        #pragma unroll
        for (int j = 0; j < 4; ++j)
            acc[i][j] = (f32x4){0.f, 0.f, 0.f, 0.f};

    const int srow = lane >> 2;
    const int skk  = (lane & 3) * 8;
    const int fr = lane & 15;
    const int fk = (lane >> 4) * 8;

    for (int k0 = 0; k0 < Dd; k0 += 32) {
        __syncthreads();
        #pragma unroll
        for (int j = 0; j < 2; ++j) {
            const int row = wave * 32 + j * 16;  // wave-uniform
            async16(A  + (size_t)(tile_m + row + srow) * Dd + k0 + skk, &sA[row * 32]);
            async16(Wt + (size_t)(tile_n + row + srow) * Dd + k0 + skk, &sB[row * 32]);
        }
        __syncthreads();

        bf16x8 af[4], bfr[4];
        #pragma unroll
        for (int mt = 0; mt < 4; ++mt)
            af[mt] = *(const bf16x8*)&sA[(wm + mt * 16 + fr) * 32 + fk];
        #pragma unroll
        for (int nt = 0; nt < 4; ++nt)
            bfr[nt] = *(const bf16x8*)&sB[(wn + nt * 16 + fr) * 32 + fk];

        #pragma unroll
        for (int mt = 0; mt < 4; ++mt)
            #pragma unroll
            for (int nt = 0; nt < 4; ++nt)
                acc[mt][nt] = __builtin_amdgcn_mfma_f32_16x16x32_bf16(
                    af[mt], bfr[nt], acc[mt][nt], 0, 0, 0);
    }

    #pragma unroll
    for (int mt = 0; mt < 4; ++mt) {
        const int row0 = tile_m + wm + mt * 16 + (lane >> 4) * 4;
        #pragma unroll
        for (int nt = 0; nt < 4; ++nt) {
            const int col = tile_n + wn + nt * 16 + (lane & 15);
            #pragma unroll
            for (int gg = 0; gg < 4; ++gg) {
                const size_t off = (size_t)(row0 + gg) * Dd + col;
                out[off] = fmaf(g, acc[mt][nt][gg], x[off]);
            }
        }
    }
}

// ---------------------------------------------------------------------------
// Mega-kernel (cooperative): P1 | grid sync | P2 | grid sync | P3.
// LDS: GEMM tiles (16KB) aliased with P1's bind/unbind/partials (9KB).
__global__ __launch_bounds__(256, 2) void k_mega(
    const float* __restrict__ x,
    const float* __restrict__ bind,
    const float* __restrict__ unbind,
    const float* __restrict__ gate,
    const float* __restrict__ decay,
    float* __restrict__ out,
    __hip_bfloat16* __restrict__ wt,
    __hip_bfloat16* __restrict__ xs,
    float* __restrict__ endv,
    float* __restrict__ c)
{
    __shared__ __align__(16) char smem[128 * 32 * 2 * 2];  // 16 KB
    __hip_bfloat16* sA = (__hip_bfloat16*)smem;
    __hip_bfloat16* sB = (__hip_bfloat16*)(smem + 128 * 32 * 2);
    float* sb = (float*)smem;               // P1 alias
    float* su = (float*)(smem + 4096);      // P1 alias
    float* sp = (float*)(smem + 8192);      // P1 alias

    const int tid = threadIdx.x;
    const int blk = blockIdx.x;
    const float dd = sigmoidf_(decay[0]);
    const int ch = blk & (NCH - 1);
    const int b  = blk >> 7;

    // ---- P1 ----
    p1_scan_end(x, dd, b, ch, tid, endv);
    if (blk >= GRID - CBL)
        p1_cblock(bind, unbind, blk - (GRID - CBL), tid, sb, su, sp, c);

    cg::this_grid().sync();

    // ---- P2 ----
    p2_scan_write(x, dd, b, ch, tid, endv, xs);
    p2_wbuild(c, blk, tid, wt);

    cg::this_grid().sync();

    // ---- P3 ----
    p3_gemm_tile(xs, wt, x, gate[0], (blk & 63) * 128, (blk >> 6) * 128,
                 tid, sA, sB, out);
}

// ---------------------------------------------------------------------------
// Fallback kernels (same math, 3 plain dispatches) — used only if the
// cooperative launch is rejected (deterministic per call).
__global__ void k_endc(const float* __restrict__ x,
                       const float* __restrict__ bind,
                       const float* __restrict__ unbind,
                       const float* __restrict__ decay,
                       float* __restrict__ endv,
                       float* __restrict__ c) {
    __shared__ float sb[Dd];
    __shared__ float su[Dd];
    __shared__ float sp[256];
    const int tid = threadIdx.x;
    const float dd = sigmoidf_(decay[0]);
    if (blockIdx.x < GRID) {
        p1_scan_end(x, dd, blockIdx.x >> 7, blockIdx.x & (NCH - 1), tid, endv);
    } else {
        p1_cblock(bind, unbind, (int)blockIdx.x - GRID, tid, sb, su, sp, c);
    }
}

__global__ void k_scanw(const float* __restrict__ x,
                        const float* __restrict__ c,
                        const float* __restrict__ decay,
                        const float* __restrict__ endv,
                        __hip_bfloat16* __restrict__ xs,
                        __hip_bfloat16* __restrict__ wt) {
    const int tid = threadIdx.x;
    if (blockIdx.x < GRID) {
        const float dd = sigmoidf_(decay[0]);
        p2_scan_write(x, dd, blockIdx.x >> 7, blockIdx.x & (NCH - 1), tid, endv, xs);
    } else {
        p2_wbuild(c, (int)blockIdx.x - GRID, tid, wt);
    }
}

__global__ __launch_bounds__(256) void k_gemm(
    const __hip_bfloat16* __restrict__ A,
    const __hip_bfloat16* __restrict__ Wt,
    const float* __restrict__ x,
    const float* __restrict__ gate,
    float* __restrict__ out) {
    __shared__ __align__(16) __hip_bfloat16 sA[128 * 32];
    __shared__ __align__(16) __hip_bfloat16 sB[128 * 32];
    p3_gemm_tile(A, Wt, x, gate[0], blockIdx.x * 128, blockIdx.y * 128,
                 threadIdx.x, sA, sB, out);
}

// ---------------------------------------------------------------------------
extern "C" void kernel_launch(void* const* d_in, const int* in_sizes, int n_in,
                              void* d_out, int out_size, void* d_ws, size_t ws_size,
                              hipStream_t stream) {
    const float* x      = (const float*)d_in[0];
    const float* bind   = (const float*)d_in[1];
    const float* unbind = (const float*)d_in[2];
    const float* gate   = (const float*)d_in[3];
    const float* decay  = (const float*)d_in[4];
    float* out = (float*)d_out;

    // workspace layout (~21 MB)
    char* ws = (char*)d_ws;
    __hip_bfloat16* wt = (__hip_bfloat16*)ws;                              // 2 MB
    __hip_bfloat16* xs = (__hip_bfloat16*)(ws + (size_t)Dd * Dd * 2);      // 16.8 MB
    float* endv = (float*)(ws + (size_t)Dd * Dd * 2 + (size_t)Rr * Dd * 2);// 2 MB
    float* c    = endv + (size_t)Bb * NCH * Dd;                            // 4 KB

    void* args[] = {
        (void*)&x, (void*)&bind, (void*)&unbind, (void*)&gate, (void*)&decay,
        (void*)&out, (void*)&wt, (void*)&xs, (void*)&endv, (void*)&c
    };
    hipError_t err = hipLaunchCooperativeKernel((const void*)k_mega, dim3(GRID),
                                                dim3(256), args, 0, stream);
    if (err != hipSuccess) {
        // deterministic fallback: same math, 3 plain dispatches
        k_endc <<<dim3(GRID + CBL),  dim3(256), 0, stream>>>(x, bind, unbind, decay, endv, c);
        k_scanw<<<dim3(GRID + GRID), dim3(256), 0, stream>>>(x, c, decay, endv, xs, wt);
        k_gemm <<<dim3(64, 8),       dim3(256), 0, stream>>>(xs, wt, x, gate, out);
    }
}

// Round 7
// 129.895 us; speedup vs baseline: 2.1374x; 2.1374x over previous
//
#include <hip/hip_runtime.h>
#include <hip/hip_bf16.h>

// Problem constants
constexpr int Dd = 1024;           // feature dim
constexpr int Tt = 2048;           // sequence length
constexpr int Bb = 4;              // batch
constexpr int Rr = Bb * Tt;        // GEMM rows = 8192
constexpr int NCH = 64;            // scan chunks
constexpr int CL  = 32;            // steps per chunk
constexpr int SCB = Bb * NCH;      // 256 scan blocks (one per (b,chunk))
constexpr int CBL = 64;            // c-reduction blocks
constexpr int WBL = 512;           // W-build blocks

typedef __attribute__((ext_vector_type(4))) float f32x4;
typedef __attribute__((ext_vector_type(16))) float f32x16;
typedef __attribute__((ext_vector_type(8))) short bf16x8;

__device__ __forceinline__ float sigmoidf_(float v) {
    return 1.0f / (1.0f + expf(-v));
}

__device__ __forceinline__ short bf16bits(float f) {
    union { __hip_bfloat16 b; short s; } u;
    u.b = __float2bfloat16(f);
    return u.s;
}

__device__ __forceinline__ void async16(const void* g, void* l) {
    __builtin_amdgcn_global_load_lds(
        (const __attribute__((address_space(1))) unsigned int*)g,
        (__attribute__((address_space(3))) unsigned int*)l,
        16, 0, 0);
}

// ---------------------------------------------------------------------------
// Kernel A: blocks [0,256): endv[b][chunk][d] = chunk-local EMA end value.
//           blocks [256,320): c[n] = sum_m unbind[m]*bind[(m+n)%D].
// grid 320 x 256
__global__ void k_endc(const float* __restrict__ x,
                       const float* __restrict__ bind,
                       const float* __restrict__ unbind,
                       const float* __restrict__ decay,
                       float* __restrict__ endv,
                       float* __restrict__ c) {
    __shared__ float sb[Dd];
    __shared__ float su[Dd];
    __shared__ float sp[256];

    const int tid = threadIdx.x;
    if (blockIdx.x < SCB) {
        const int chunk = blockIdx.x & (NCH - 1);
        const int b = blockIdx.x >> 6;
        const float dd = sigmoidf_(decay[0]);
        const size_t base = ((size_t)b * Tt + (size_t)chunk * CL) * Dd + tid * 4;
        f32x4 e = (f32x4){0.f, 0.f, 0.f, 0.f};
        #pragma unroll 8
        for (int t = 0; t < CL; ++t) {
            f32x4 v = *(const f32x4*)&x[base + (size_t)t * Dd];
            e = dd * e + v;
        }
        *(f32x4*)&endv[((size_t)b * NCH + chunk) * Dd + tid * 4] = e;
    } else {
        for (int j = tid; j < Dd; j += 256) { sb[j] = bind[j]; su[j] = unbind[j]; }
        __syncthreads();
        const int n_loc = tid >> 4;
        const int seg = tid & 15;
        const int n = (int)(blockIdx.x - SCB) * 16 + n_loc;
        float acc = 0.f;
        #pragma unroll 8
        for (int i = 0; i < 64; ++i) {
            const int m = i * 16 + seg;
            acc = fmaf(su[m], sb[(m + n) & (Dd - 1)], acc);
        }
        sp[tid] = acc;
        __syncthreads();
        if (tid < 16) {
            float s = 0.f;
            #pragma unroll
            for (int j = 0; j < 16; ++j) s += sp[tid * 16 + j];
            c[(int)(blockIdx.x - SCB) * 16 + tid] = s;
        }
    }
}

// ---------------------------------------------------------------------------
// Kernel B: blocks [0,256): full scan with carry injected, write bf16 xs once.
//           blocks [256,768): Wt[n][k] = bf16(c[(n-k) mod D]).
// grid 768 x 256
__global__ void k_scanw(const float* __restrict__ x,
                        const float* __restrict__ c,
                        const float* __restrict__ decay,
                        const float* __restrict__ endv,
                        __hip_bfloat16* __restrict__ xs,
                        __hip_bfloat16* __restrict__ wt) {
    const int tid = threadIdx.x;
    if (blockIdx.x < SCB) {
        const int chunk = blockIdx.x & (NCH - 1);
        const int b = blockIdx.x >> 6;
        const float dd = sigmoidf_(decay[0]);
        const float dL = powf(dd, (float)CL);
        // carry recombine: independent loads, pipelined by unroll
        f32x4 h = (f32x4){0.f, 0.f, 0.f, 0.f};
        const float* ep = endv + ((size_t)b * NCH) * Dd + tid * 4;
        #pragma unroll 8
        for (int cc = 0; cc < chunk; ++cc)
            h = dL * h + *(const f32x4*)&ep[(size_t)cc * Dd];
        // scan CL steps, write bf16x4 (8B/lane)
        const size_t base = ((size_t)b * Tt + (size_t)chunk * CL) * Dd + tid * 4;
        #pragma unroll 8
        for (int t = 0; t < CL; ++t) {
            f32x4 v = *(const f32x4*)&x[base + (size_t)t * Dd];
            h = dd * h + v;
            short4 o;
            o.x = bf16bits(h[0]); o.y = bf16bits(h[1]);
            o.z = bf16bits(h[2]); o.w = bf16bits(h[3]);
            *(short4*)&xs[base + (size_t)t * Dd] = o;
        }
    } else {
        const int idx8 = (int)(blockIdx.x - SCB) * 256 + tid;
        const int n = idx8 >> 7;
        const int k0 = (idx8 & 127) * 8;
        bf16x8 v;
        #pragma unroll
        for (int j = 0; j < 8; ++j)
            v[j] = bf16bits(c[(n - (k0 + j)) & (Dd - 1)]);
        *(bf16x8*)&wt[(size_t)n * Dd + k0] = v;
    }
}

// ---------------------------------------------------------------------------
// Kernel C: out[r][n] = x[r][n] + gate * sum_k xs[r][k] * Wt[n][k]
// 128x128 tile, BK=32, 4 waves 2x2 (64x64 each), 32x32x16 bf16 MFMA
// (2x2 sub-tiles of 32x32 per wave), async LDS staging.
// grid (64, 8) x 256
__global__ __launch_bounds__(256) void k_gemm(
    const __hip_bfloat16* __restrict__ A,   // [R][D] bf16 (scanned x)
    const __hip_bfloat16* __restrict__ Wt,  // [D][D] bf16, Wt[n][k]
    const float* __restrict__ x,            // [R][D] fp32
    const float* __restrict__ gate,         // [1]
    float* __restrict__ out)                // [R][D] fp32
{
    __shared__ __align__(16) __hip_bfloat16 sA[128 * 32];
    __shared__ __align__(16) __hip_bfloat16 sB[128 * 32];

    const int tid = threadIdx.x;
    const int wave = tid >> 6;
    const int lane = tid & 63;
    const int tile_m = blockIdx.x * 128;
    const int tile_n = blockIdx.y * 128;
    const int wm = (wave & 1) * 64;
    const int wn = (wave >> 1) * 64;

    f32x16 acc[2][2];
    #pragma unroll
    for (int i = 0; i < 2; ++i)
        #pragma unroll
        for (int j = 0; j < 2; ++j)
            #pragma unroll
            for (int e = 0; e < 16; ++e)
                acc[i][j][e] = 0.f;

    const int srow = lane >> 2;        // staging: 16-row group
    const int skk  = (lane & 3) * 8;   // staging: 16B k-chunk
    const int fm = lane & 31;          // fragment m/n index
    const int fko = (lane >> 5) * 8;   // fragment k base (0 or 8)

    for (int k0 = 0; k0 < Dd; k0 += 32) {
        __syncthreads();
        #pragma unroll
        for (int j = 0; j < 2; ++j) {
            const int row = wave * 32 + j * 16;  // wave-uniform
            async16(A  + (size_t)(tile_m + row + srow) * Dd + k0 + skk, &sA[row * 32]);
            async16(Wt + (size_t)(tile_n + row + srow) * Dd + k0 + skk, &sB[row * 32]);
        }
        __syncthreads();

        // A[m][k]: m = lane&31 (+32*subm), k = (lane>>5)*8 + j (+16*kh)
        bf16x8 af[2][2], bfr[2][2];
        #pragma unroll
        for (int sm = 0; sm < 2; ++sm)
            #pragma unroll
            for (int kh = 0; kh < 2; ++kh)
                af[sm][kh] = *(const bf16x8*)&sA[(wm + sm * 32 + fm) * 32 + kh * 16 + fko];
        #pragma unroll
        for (int sn = 0; sn < 2; ++sn)
            #pragma unroll
            for (int kh = 0; kh < 2; ++kh)
                bfr[sn][kh] = *(const bf16x8*)&sB[(wn + sn * 32 + fm) * 32 + kh * 16 + fko];

        #pragma unroll
        for (int sm = 0; sm < 2; ++sm)
            #pragma unroll
            for (int sn = 0; sn < 2; ++sn)
                #pragma unroll
                for (int kh = 0; kh < 2; ++kh)
                    acc[sm][sn] = __builtin_amdgcn_mfma_f32_32x32x16_bf16(
                        af[sm][kh], bfr[sn][kh], acc[sm][sn], 0, 0, 0);
    }

    // C/D layout (verified m74/m101): col = lane&31, row = (reg&3) + 8*(reg>>2) + 4*(lane>>5)
    const float g = gate[0];
    #pragma unroll
    for (int sm = 0; sm < 2; ++sm) {
        #pragma unroll
        for (int sn = 0; sn < 2; ++sn) {
            const int colg = tile_n + wn + sn * 32 + (lane & 31);
            #pragma unroll
            for (int g1 = 0; g1 < 4; ++g1) {
                const int row0 = tile_m + wm + sm * 32 + g1 * 8 + (lane >> 5) * 4;
                #pragma unroll
                for (int r0 = 0; r0 < 4; ++r0) {
                    const size_t off = (size_t)(row0 + r0) * Dd + colg;
                    out[off] = fmaf(g, acc[sm][sn][g1 * 4 + r0], x[off]);
                }
            }
        }
    }
}

// ---------------------------------------------------------------------------
extern "C" void kernel_launch(void* const* d_in, const int* in_sizes, int n_in,
                              void* d_out, int out_size, void* d_ws, size_t ws_size,
                              hipStream_t stream) {
    const float* x      = (const float*)d_in[0];
    const float* bind   = (const float*)d_in[1];
    const float* unbind = (const float*)d_in[2];
    const float* gate   = (const float*)d_in[3];
    const float* decay  = (const float*)d_in[4];
    float* out = (float*)d_out;

    // workspace layout (~19.8 MB)
    char* ws = (char*)d_ws;
    __hip_bfloat16* wt = (__hip_bfloat16*)ws;                              // 2 MB
    __hip_bfloat16* xs = (__hip_bfloat16*)(ws + (size_t)Dd * Dd * 2);      // 16.8 MB
    float* endv = (float*)(ws + (size_t)Dd * Dd * 2 + (size_t)Rr * Dd * 2);// 1 MB
    float* c    = endv + (size_t)Bb * NCH * Dd;                            // 4 KB

    k_endc <<<dim3(SCB + CBL), dim3(256), 0, stream>>>(x, bind, unbind, decay, endv, c);
    k_scanw<<<dim3(SCB + WBL), dim3(256), 0, stream>>>(x, c, decay, endv, xs, wt);
    k_gemm <<<dim3(64, 8),     dim3(256), 0, stream>>>(xs, wt, x, gate, out);
}